// Round 2
// baseline (265.511 us; speedup 1.0000x reference)
//
#include <hip/hip_runtime.h>

// EquivariantLinear: out[pos, c, m] = pw * sum_k x[pos, k, m] * W_{l(m)}[k, c]
// pos = 32768, C_IN = C_OUT = 256, FEAT = 9 (irreps 1,3,5), pw = 1/16.
// R4: back to one-shot R2 structure (no persistence, no per-tile barriers that
// drain stores). POSB=8 with two m-planes packed per 16-row MFMA tile
// (pairs within an irrep share the B operand):
//   T0{m0,-} T1{m1,m2} T2{m3,-} T3{m4,m5} T4{m6,m7} T5{m8,-}
// Each wave computes 16 output channels (acc = 6 f32x4 = 24 AGPR), block =
// (8 pos) x (128 c), grid = 4096 pos-tiles x 2 c-halves = 8192 blocks.
// LDS 38,016 B/block -> 3-4 blocks/CU (24-32 waves) vs R2's 2 (16 waves).
// c-twin blocks are 8 apart in blockIdx -> same XCD under RR dispatch -> the
// duplicate x-tile read hits L2/L3 instead of HBM.

typedef float f32x4 __attribute__((ext_vector_type(4)));
typedef short s16x8 __attribute__((ext_vector_type(8)));

#define POSB 8                       // positions per tile
#define XS_KS 264                    // padded k-stride (elems)
#define XS_MS (POSB * XS_KS)         // 2112 elems per m-plane
#define SMEM_BYTES (9 * XS_MS * 2)   // 38016 B
#define STG_ROW 148                  // out-stage row stride (floats); 144 used
// per-wave out-stage: 8*148*4 = 4736 B; 8 waves = 37888 <= 38016 (aliases xs)

__device__ __forceinline__ unsigned short f2bf(float f) {
  unsigned u = __float_as_uint(f);
  return (unsigned short)((u + 0x7FFFu + ((u >> 16) & 1u)) >> 16);
}

// ---- prep: W^T bf16 image in ws: wt[irr][c][k] = pw * w_irr[k][c] ----
__global__ void prep_w(const float* __restrict__ w0, const float* __restrict__ w1,
                       const float* __restrict__ w2, unsigned short* __restrict__ wt) {
  const int b = blockIdx.x;
  const int irr = b / 16;
  const int tile = b % 16;
  const int k0 = (tile >> 2) << 6;
  const int c0 = (tile & 3) << 6;
  const float* w = (irr == 0) ? w0 : ((irr == 1) ? w1 : w2);
  __shared__ float lt[64 * 65];
  const int t = threadIdx.x;
#pragma unroll
  for (int i = 0; i < 16; ++i) {
    int e = t + (i << 8);
    int kk = e >> 6, cc = e & 63;
    lt[cc * 65 + kk] = w[(k0 + kk) * 256 + (c0 + cc)];
  }
  __syncthreads();
#pragma unroll
  for (int i = 0; i < 16; ++i) {
    int e = t + (i << 8);
    int cc = e >> 6, kk = e & 63;
    wt[irr * 65536 + (c0 + cc) * 256 + (k0 + kk)] = f2bf(lt[cc * 65 + kk] * 0.0625f);
  }
}

// ---- main: 8192 blocks x 512 threads (8 waves) ----
__global__ __launch_bounds__(512, 6) void eqlin_main(
    const float* __restrict__ x, const unsigned short* __restrict__ wt,
    float* __restrict__ out) {
  extern __shared__ char smem[];
  unsigned short* xs = reinterpret_cast<unsigned short*>(smem);  // [9][8][264] bf16

  const int t = threadIdx.x;
  const int b = blockIdx.x;
  // twins (same pos-tile, other c-half) are 8 apart -> same XCD under RR
  const int grp = b >> 4;
  const int sub = b & 15;
  const int tile = (grp << 3) | (sub & 7);   // 0..4095
  const int chalf = sub >> 3;                // 0..1

  const float* xb = x + (long long)tile * (POSB * 2304);

  // ---- stage x -> LDS bf16 [m][pos][k]: one (pos, kquad) unit per thread ----
  {
    const int pos = t >> 6;            // 0..7
    const int kq = (t & 63) << 2;      // k base, multiple of 4
    const f32x4* src = reinterpret_cast<const f32x4*>(xb) + t * 9;  // 144 B chunk
    float f[36];
#pragma unroll
    for (int j = 0; j < 9; ++j) {
      f32x4 v = src[j];
      f[j * 4 + 0] = v[0]; f[j * 4 + 1] = v[1];
      f[j * 4 + 2] = v[2]; f[j * 4 + 3] = v[3];
    }
#pragma unroll
    for (int m = 0; m < 9; ++m) {
      unsigned long long pk =
          (unsigned long long)f2bf(f[m]) |
          ((unsigned long long)f2bf(f[9 + m]) << 16) |
          ((unsigned long long)f2bf(f[18 + m]) << 32) |
          ((unsigned long long)f2bf(f[27 + m]) << 48);
      *reinterpret_cast<unsigned long long*>(xs + m * XS_MS + pos * XS_KS + kq) = pk;
    }
  }
  __syncthreads();

  const int w = t >> 6;
  const int l = t & 63;
  const int cr = l & 15;          // A row sel / B col (=c in 16-wide group)
  const int kg = (l >> 4) << 3;   // k-chunk base 0/8/16/24
  const int cb = chalf * 128 + (w << 4);     // 16 channels per wave

  const unsigned short* wtB = wt + (cb + cr) * 256 + kg;

  // plane pairs per tile: rows 0-7 -> pA, rows 8-15 -> pB (pad: pB==pA)
  const bool hi = (cr >= 8);
  const unsigned short* xrow = xs + (cr & 7) * XS_KS + kg;
  const unsigned short* xa[6] = {
      xrow + 0 * XS_MS,                    // T0 {0,0}
      xrow + (hi ? 2 : 1) * XS_MS,         // T1 {1,2}
      xrow + 3 * XS_MS,                    // T2 {3,3}
      xrow + (hi ? 5 : 4) * XS_MS,         // T3 {4,5}
      xrow + (hi ? 7 : 6) * XS_MS,         // T4 {6,7}
      xrow + 8 * XS_MS,                    // T5 {8,8}
  };

  f32x4 acc[6];
#pragma unroll
  for (int T = 0; T < 6; ++T) acc[T] = (f32x4){0.f, 0.f, 0.f, 0.f};

#pragma unroll
  for (int ks = 0; ks < 8; ++ks) {
    const int kk = ks << 5;
    s16x8 b0 = *reinterpret_cast<const s16x8*>(wtB + kk);
    s16x8 b1 = *reinterpret_cast<const s16x8*>(wtB + 65536 + kk);
    s16x8 b2 = *reinterpret_cast<const s16x8*>(wtB + 131072 + kk);
    s16x8 a0 = *reinterpret_cast<const s16x8*>(xa[0] + kk);
    acc[0] = __builtin_amdgcn_mfma_f32_16x16x32_bf16(a0, b0, acc[0], 0, 0, 0);
    s16x8 a1 = *reinterpret_cast<const s16x8*>(xa[1] + kk);
    acc[1] = __builtin_amdgcn_mfma_f32_16x16x32_bf16(a1, b1, acc[1], 0, 0, 0);
    s16x8 a2 = *reinterpret_cast<const s16x8*>(xa[2] + kk);
    acc[2] = __builtin_amdgcn_mfma_f32_16x16x32_bf16(a2, b1, acc[2], 0, 0, 0);
    s16x8 a3 = *reinterpret_cast<const s16x8*>(xa[3] + kk);
    acc[3] = __builtin_amdgcn_mfma_f32_16x16x32_bf16(a3, b2, acc[3], 0, 0, 0);
    s16x8 a4 = *reinterpret_cast<const s16x8*>(xa[4] + kk);
    acc[4] = __builtin_amdgcn_mfma_f32_16x16x32_bf16(a4, b2, acc[4], 0, 0, 0);
    s16x8 a5 = *reinterpret_cast<const s16x8*>(xa[5] + kk);
    acc[5] = __builtin_amdgcn_mfma_f32_16x16x32_bf16(a5, b2, acc[5], 0, 0, 0);
  }
  __syncthreads();  // xs fully consumed by ALL waves; stage may alias it

  // ---- per-wave out-stage (4736 B slice of smem), wave-internal sync only ----
  float* stgw = reinterpret_cast<float*>(smem) + w * (POSB * STG_ROW);
  const int gq = l >> 4;               // 0..3
  const int jb = (gq & 1) << 2;        // pos base 0/4 (row = gq*4+j; pos = row&7)

  // scatter acc -> stgw[pos][cr*9 + m]
  const int pAt[6] = {0, 1, 3, 4, 6, 8};
  const int pBt[6] = {0, 2, 3, 5, 7, 8};
#pragma unroll
  for (int T = 0; T < 6; ++T) {
    const int m = (gq < 2) ? pAt[T] : pBt[T];
    if (gq < 2 || pAt[T] != pBt[T]) {   // pads: rows 8-15 are duplicates, skip
#pragma unroll
      for (int j = 0; j < 4; ++j)
        stgw[(jb + j) * STG_ROW + cr * 9 + m] = acc[T][j];
    }
  }
  asm volatile("s_waitcnt lgkmcnt(0)" ::: "memory");

  // coalesced float4 store of this wave's contiguous 8pos x 16c x 9m slice
  const long long obase = (long long)tile * (POSB * 576) + chalf * 288 + w * 36;
  f32x4* o4 = reinterpret_cast<f32x4*>(out);
#pragma unroll
  for (int q = 0; q < 5; ++q) {
    const int e = l + (q << 6);                 // 0..287 float4s (last iter half)
    if (e < 288) {
      const int pos = (int)((unsigned)e / 36u);
      const int rem = e - pos * 36;
      f32x4 v = *reinterpret_cast<const f32x4*>(stgw + pos * STG_ROW + (rem << 2));
      o4[obase + (long long)pos * 576 + rem] = v;
    }
  }
}

extern "C" void kernel_launch(void* const* d_in, const int* in_sizes, int n_in,
                              void* d_out, int out_size, void* d_ws, size_t ws_size,
                              hipStream_t stream) {
  const float* x = (const float*)d_in[0];
  const float* w0 = (const float*)d_in[1];
  const float* w1 = (const float*)d_in[2];
  const float* w2 = (const float*)d_in[3];
  unsigned short* wt = (unsigned short*)d_ws;  // 3*256*256 bf16 = 384 KB
  float* out = (float*)d_out;

  prep_w<<<48, 256, 0, stream>>>(w0, w1, w2, wt);

  (void)hipFuncSetAttribute(reinterpret_cast<const void*>(eqlin_main),
                            hipFuncAttributeMaxDynamicSharedMemorySize, SMEM_BYTES);
  eqlin_main<<<8192, 512, SMEM_BYTES, stream>>>(x, wt, out);
}

// Round 3
// 213.378 us; speedup vs baseline: 1.2443x; 1.2443x over previous
//
#include <hip/hip_runtime.h>

// EquivariantLinear: out[pos, c, m] = pw * sum_k x[pos, k, m] * W_{l(m)}[k, c]
// pos = 32768, C_IN = C_OUT = 256, FEAT = 9 (irreps 1,3,5), pw = 1/16.
// R5 = R2 structure (2048 blocks x 512 thr, POSB=16, 76KB LDS, 2 blk/CU) with
// the out-stage LDS round-trip DELETED: the MFMA C layout already gives each
// lane all 9 m of a (pos, c) pair -> store 36 B/lane straight from registers
// (2x dwordx4 + dword, 4-B aligned; 16 cr-lanes cover a dense 576-B span).
// Kills ~600 MB LDS traffic, the 2nd __syncthreads, and both lgkmcnt drains.

typedef float f32x4 __attribute__((ext_vector_type(4)));
typedef float f32x4u __attribute__((ext_vector_type(4), aligned(4)));
typedef short s16x8 __attribute__((ext_vector_type(8)));

#define POSB 16                      // positions per block
#define XS_KS 264                    // padded k-stride (elems)
#define XS_MS (POSB * XS_KS)         // 4224 elems per m-plane
#define SMEM_BYTES (9 * XS_MS * 2)   // 76032 B

__device__ __forceinline__ unsigned short f2bf(float f) {
  unsigned u = __float_as_uint(f);
  return (unsigned short)((u + 0x7FFFu + ((u >> 16) & 1u)) >> 16);
}

// ---- prep: W^T bf16 image in ws: wt[irr][c][k] = pw * w_irr[k][c] ----
__global__ void prep_w(const float* __restrict__ w0, const float* __restrict__ w1,
                       const float* __restrict__ w2, unsigned short* __restrict__ wt) {
  const int b = blockIdx.x;
  const int irr = b / 16;
  const int tile = b % 16;
  const int k0 = (tile >> 2) << 6;
  const int c0 = (tile & 3) << 6;
  const float* w = (irr == 0) ? w0 : ((irr == 1) ? w1 : w2);
  __shared__ float lt[64 * 65];
  const int t = threadIdx.x;
#pragma unroll
  for (int i = 0; i < 16; ++i) {
    int e = t + (i << 8);
    int kk = e >> 6, cc = e & 63;
    lt[cc * 65 + kk] = w[(k0 + kk) * 256 + (c0 + cc)];
  }
  __syncthreads();
#pragma unroll
  for (int i = 0; i < 16; ++i) {
    int e = t + (i << 8);
    int cc = e >> 6, kk = e & 63;
    wt[irr * 65536 + (c0 + cc) * 256 + (k0 + kk)] = f2bf(lt[cc * 65 + kk] * 0.0625f);
  }
}

// ---- main: 2048 blocks x 512 threads (8 waves), 2 blocks/CU ----
__global__ __launch_bounds__(512, 4) void eqlin_main(
    const float* __restrict__ x, const unsigned short* __restrict__ wt,
    float* __restrict__ out) {
  extern __shared__ char smem[];
  unsigned short* xs = reinterpret_cast<unsigned short*>(smem);  // [9][16][264] bf16

  const int t = threadIdx.x;
  const long long blk = blockIdx.x;
  const float* xb = x + blk * (POSB * 2304);

  // ---- stage x -> LDS bf16 [m][pos][k]: per-lane gather of 4k x 9m (144 B),
  //      conflict-free stride-8B ds_write_b64 per m-plane ----
#pragma unroll
  for (int i = 0; i < 2; ++i) {
    const int p = t + (i << 9);        // 0..1023 = pos(4b) x kquad(6b)
    const int pos = p >> 6;
    const int kq = (p & 63) << 2;      // k base, multiple of 4
    const f32x4* src = reinterpret_cast<const f32x4*>(xb) + p * 9;  // 144 B chunk
    float f[36];
#pragma unroll
    for (int j = 0; j < 9; ++j) {
      f32x4 v = src[j];
      f[j * 4 + 0] = v[0]; f[j * 4 + 1] = v[1];
      f[j * 4 + 2] = v[2]; f[j * 4 + 3] = v[3];
    }
#pragma unroll
    for (int m = 0; m < 9; ++m) {
      unsigned long long pk =
          (unsigned long long)f2bf(f[m]) |
          ((unsigned long long)f2bf(f[9 + m]) << 16) |
          ((unsigned long long)f2bf(f[18 + m]) << 32) |
          ((unsigned long long)f2bf(f[27 + m]) << 48);
      *reinterpret_cast<unsigned long long*>(xs + m * XS_MS + pos * XS_KS + kq) = pk;
    }
  }
  __syncthreads();

  const int w = t >> 6;
  const int l = t & 63;
  const int cr = l & 15;          // A row (=pos) / B col (=c in tile)
  const int kg = (l >> 4) << 3;   // k-chunk base 0/8/16/24
  const int c0 = w << 5;          // 32 channels per wave

  const unsigned short* xsA = xs + cr * XS_KS + kg;
  const unsigned short* wtB = wt + (c0 + cr) * 256 + kg;

  f32x4 accA[4][2];  // m = 0..3
#pragma unroll
  for (int m = 0; m < 4; ++m)
#pragma unroll
    for (int ct = 0; ct < 2; ++ct) accA[m][ct] = (f32x4){0.f, 0.f, 0.f, 0.f};

  // pass 1: m 0..3 (irr0 for m0, irr1 for m1..3)
#pragma unroll 2
  for (int ks = 0; ks < 8; ++ks) {
    const int kk = ks << 5;
    s16x8 b00 = *reinterpret_cast<const s16x8*>(wtB + kk);
    s16x8 b01 = *reinterpret_cast<const s16x8*>(wtB + 4096 + kk);
    s16x8 b10 = *reinterpret_cast<const s16x8*>(wtB + 65536 + kk);
    s16x8 b11 = *reinterpret_cast<const s16x8*>(wtB + 65536 + 4096 + kk);
    {
      s16x8 a = *reinterpret_cast<const s16x8*>(xsA + kk);
      accA[0][0] = __builtin_amdgcn_mfma_f32_16x16x32_bf16(a, b00, accA[0][0], 0, 0, 0);
      accA[0][1] = __builtin_amdgcn_mfma_f32_16x16x32_bf16(a, b01, accA[0][1], 0, 0, 0);
    }
#pragma unroll
    for (int m = 1; m < 4; ++m) {
      s16x8 a = *reinterpret_cast<const s16x8*>(xsA + m * XS_MS + kk);
      accA[m][0] = __builtin_amdgcn_mfma_f32_16x16x32_bf16(a, b10, accA[m][0], 0, 0, 0);
      accA[m][1] = __builtin_amdgcn_mfma_f32_16x16x32_bf16(a, b11, accA[m][1], 0, 0, 0);
    }
  }

  f32x4 accB[5][2];  // m = 4..8 (irr2)
#pragma unroll
  for (int m = 0; m < 5; ++m)
#pragma unroll
    for (int ct = 0; ct < 2; ++ct) accB[m][ct] = (f32x4){0.f, 0.f, 0.f, 0.f};

  // pass 2: m 4..8
#pragma unroll 2
  for (int ks = 0; ks < 8; ++ks) {
    const int kk = ks << 5;
    s16x8 b20 = *reinterpret_cast<const s16x8*>(wtB + 2 * 65536 + kk);
    s16x8 b21 = *reinterpret_cast<const s16x8*>(wtB + 2 * 65536 + 4096 + kk);
#pragma unroll
    for (int m = 0; m < 5; ++m) {
      s16x8 a = *reinterpret_cast<const s16x8*>(xsA + (m + 4) * XS_MS + kk);
      accB[m][0] = __builtin_amdgcn_mfma_f32_16x16x32_bf16(a, b20, accB[m][0], 0, 0, 0);
      accB[m][1] = __builtin_amdgcn_mfma_f32_16x16x32_bf16(a, b21, accB[m][1], 0, 0, 0);
    }
  }

  // ---- direct register -> global store: lane (g, cr) owns c = c0+ct*16+cr,
  //      pos = 4g+j, all 9 m contiguous (36 B) ----
  const int g = l >> 4;  // 0..3
#pragma unroll
  for (int ct = 0; ct < 2; ++ct) {
    const int c = c0 + (ct << 4) + cr;
#pragma unroll
    for (int j = 0; j < 4; ++j) {
      float* o = out + ((blk * POSB + (g << 2) + j) * 256 + c) * 9;
      f32x4u v0 = {accA[0][ct][j], accA[1][ct][j], accA[2][ct][j], accA[3][ct][j]};
      f32x4u v1 = {accB[0][ct][j], accB[1][ct][j], accB[2][ct][j], accB[3][ct][j]};
      *reinterpret_cast<f32x4u*>(o) = v0;
      *reinterpret_cast<f32x4u*>(o + 4) = v1;
      o[8] = accB[4][ct][j];
    }
  }
}

extern "C" void kernel_launch(void* const* d_in, const int* in_sizes, int n_in,
                              void* d_out, int out_size, void* d_ws, size_t ws_size,
                              hipStream_t stream) {
  const float* x = (const float*)d_in[0];
  const float* w0 = (const float*)d_in[1];
  const float* w1 = (const float*)d_in[2];
  const float* w2 = (const float*)d_in[3];
  unsigned short* wt = (unsigned short*)d_ws;  // 3*256*256 bf16 = 384 KB
  float* out = (float*)d_out;

  prep_w<<<48, 256, 0, stream>>>(w0, w1, w2, wt);

  (void)hipFuncSetAttribute(reinterpret_cast<const void*>(eqlin_main),
                            hipFuncAttributeMaxDynamicSharedMemorySize, SMEM_BYTES);
  eqlin_main<<<2048, 512, SMEM_BYTES, stream>>>(x, wt, out);
}